// Round 15
// baseline (134.964 us; speedup 1.0000x reference)
//
#include <hip/hip_runtime.h>
#include <hip/hip_bf16.h>
#include <math.h>

#define B_  2
#define S_  2048
#define E_  1024
#define NH_ 4
#define DH_ 256
#define EPSF 1e-6f

typedef __attribute__((ext_vector_type(4)))  short  s16x4;
typedef __attribute__((ext_vector_type(8)))  short  s16x8;
typedef __attribute__((ext_vector_type(8)))  __bf16 bf16x8;
typedef __attribute__((ext_vector_type(4)))  float  f32x4;
typedef __attribute__((ext_vector_type(16))) float  f32x16;

static __device__ __forceinline__ short f2bf(float f) {
    unsigned u = __builtin_bit_cast(unsigned, f);
    u = (u + 0x7FFFu + ((u >> 16) & 1u)) >> 16;
    return (short)u;
}

static __device__ __forceinline__ void gload16(const void* g, void* l) {
    __builtin_amdgcn_global_load_lds(
        (__attribute__((address_space(1))) void*)g,
        (__attribute__((address_space(3))) void*)l, 16, 0, 0);
}

// ---------------- prep: fused convert(q,k)+gates [0..511] and v-transpose [512..1535]
__global__ __launch_bounds__(256)
void prep_kernel(const float* __restrict__ q, const float* __restrict__ k,
                 const float* __restrict__ v,
                 const float* __restrict__ igk, const float* __restrict__ igb,
                 const float* __restrict__ fgk, const float* __restrict__ fgb,
                 short* __restrict__ qbf, short* __restrict__ kbf,
                 short* __restrict__ vt,
                 float* __restrict__ ig_ws, float* __restrict__ fg_ws) {
    const int bid = blockIdx.x;
    if (bid < 512) {
        int wid = threadIdx.x >> 6, lane = threadIdx.x & 63;
        int row0 = (bid * 4 + wid) * 2;
        int b = row0 >> 11;
        int s0 = row0 & 2047;
        float accI[2][4] = {};
        float accF[2][4] = {};
        const float* srcs[3] = {q, k, v};
        short* dsts[2] = {qbf, kbf};
#pragma unroll
        for (int p = 0; p < 3; p++) {
            const float* src = srcs[p] + ((long)b * S_ + s0) * E_;
#pragma unroll
            for (int c = 0; c < 4; c++) {
                int e = c * 256 + lane * 4;
                float4 x0 = *(const float4*)(src + e);
                float4 x1 = *(const float4*)(src + E_ + e);
                if (p < 2) {
                    s16x4 o0, o1;
                    o0[0] = f2bf(x0.x); o0[1] = f2bf(x0.y); o0[2] = f2bf(x0.z); o0[3] = f2bf(x0.w);
                    o1[0] = f2bf(x1.x); o1[1] = f2bf(x1.y); o1[2] = f2bf(x1.z); o1[3] = f2bf(x1.w);
                    long db = ((long)(b * NH_ + c) * S_ + s0) * DH_ + lane * 4;
                    *(s16x4*)(dsts[p] + db) = o0;
                    *(s16x4*)(dsts[p] + db + DH_) = o1;
                }
                const float4* wi = (const float4*)(igk + (long)(p * E_ + e) * 4);
                const float4* wf = (const float4*)(fgk + (long)(p * E_ + e) * 4);
                float xs0[4] = {x0.x, x0.y, x0.z, x0.w};
                float xs1[4] = {x1.x, x1.y, x1.z, x1.w};
#pragma unroll
                for (int j = 0; j < 4; j++) {
                    float4 wij = wi[j], wfj = wf[j];
                    accI[0][0] += xs0[j] * wij.x; accI[0][1] += xs0[j] * wij.y;
                    accI[0][2] += xs0[j] * wij.z; accI[0][3] += xs0[j] * wij.w;
                    accF[0][0] += xs0[j] * wfj.x; accF[0][1] += xs0[j] * wfj.y;
                    accF[0][2] += xs0[j] * wfj.z; accF[0][3] += xs0[j] * wfj.w;
                    accI[1][0] += xs1[j] * wij.x; accI[1][1] += xs1[j] * wij.y;
                    accI[1][2] += xs1[j] * wij.z; accI[1][3] += xs1[j] * wij.w;
                    accF[1][0] += xs1[j] * wfj.x; accF[1][1] += xs1[j] * wfj.y;
                    accF[1][2] += xs1[j] * wfj.z; accF[1][3] += xs1[j] * wfj.w;
                }
            }
        }
#pragma unroll
        for (int r = 0; r < 2; r++) {
#pragma unroll
            for (int hh = 0; hh < 4; hh++) {
                float aI = accI[r][hh], aF = accF[r][hh];
                for (int m = 1; m < 64; m <<= 1) { aI += __shfl_xor(aI, m); aF += __shfl_xor(aF, m); }
                if (lane == 0) {
                    ig_ws[((long)(b * NH_ + hh)) * S_ + s0 + r] = aI + igb[hh];
                    fg_ws[((long)(b * NH_ + hh)) * S_ + s0 + r] = aF + fgb[hh];
                }
            }
        }
    } else {
        __shared__ short tile[64][66];
        int b2 = bid - 512;
        int dt = b2 & 3, st = (b2 >> 2) & 31, hh = (b2 >> 7) & 3, b = b2 >> 9;
        int t = threadIdx.x;
#pragma unroll
        for (int rep = 0; rep < 16; rep++) {
            int idx = t + rep * 256;
            int ts = idx >> 6, td = idx & 63;
            float x = v[((long)b * S_ + st * 64 + ts) * E_ + hh * DH_ + dt * 64 + td];
            tile[ts][td] = f2bf(x);
        }
        __syncthreads();
        long obase = ((long)(b * NH_ + hh) * DH_ + dt * 64) * S_ + st * 64;
#pragma unroll
        for (int rep = 0; rep < 8; rep++) {
            int idx = t + rep * 256;
            int dd = idx >> 5, sp = (idx & 31) * 2;
            short2 val;
            val.x = tile[sp][dd];
            val.y = tile[sp + 1][dd];
            *(short2*)(vt + obase + (long)dd * S_ + sp) = val;
        }
    }
}

// ---------------- scan: 1024 threads/seq -> 2 serial chunks
__global__ __launch_bounds__(1024)
void scan_kernel(const float* __restrict__ ig_ws, const float* __restrict__ fg_ws,
                 float* __restrict__ c_ws, float* __restrict__ a_ws,
                 float* __restrict__ M_ws) {
    __shared__ float wsum[16], wmax[16];
    int seq = blockIdx.x;
    int tid = threadIdx.x, w = tid >> 6, lane = tid & 63;
    long base = (long)seq * S_;
    float carryC = 0.f, carryM = -INFINITY;
    for (int ch = 0; ch < S_ / 1024; ch++) {
        int s = ch * 1024 + tid;
        float fgv = fg_ws[base + s];
        float lf = (fgv > 0.f) ? -log1pf(expf(-fgv)) : (fgv - log1pf(expf(fgv)));
        float x = lf;
        for (int d = 1; d < 64; d <<= 1) { float t = __shfl_up(x, d); if (lane >= d) x += t; }
        if (lane == 63) wsum[w] = x;
        __syncthreads();
        float pre = carryC;
        for (int j = 0; j < w; j++) pre += wsum[j];
        float c = pre + x;
        float a = ig_ws[base + s] - c;
        float m = a;
        for (int d = 1; d < 64; d <<= 1) { float t = __shfl_up(m, d); if (lane >= d) m = fmaxf(m, t); }
        if (lane == 63) wmax[w] = m;
        __syncthreads();
        float prem = carryM;
        for (int j = 0; j < w; j++) prem = fmaxf(prem, wmax[j]);
        float M = fmaxf(prem, m);
        c_ws[base + s] = c;
        a_ws[base + s] = a;
        M_ws[base + s] = M;
        float allsum = 0.f, allmax = -INFINITY;
        for (int j = 0; j < 16; j++) { allsum += wsum[j]; allmax = fmaxf(allmax, wmax[j]); }
        carryC += allsum;
        carryM = fmaxf(carryM, allmax);
        __syncthreads();
    }
}

// ================= split-K main + in-block epilogue for direct tiles.
// grid 384: seq = bid&7, local = bid>>3 in [0,48):
//   local <32: split qt = 31-(local>>1), chunk = local&1, pq=(qt-16)*2+chunk
//   local>=32: direct qt = 47-local, full range, epilogue in-block -> out
// LDS 72KB: K 32K | V 32K | P 8K. K/Q use 32-slot swizzle ^((r&31)<<4) ->
// conflict-free b128 reads; V/P keep 8-slot (128B rows). T5 setprio on MFMA.
__global__ __launch_bounds__(256)
void mlstm_sb1(const short* __restrict__ qbf, const short* __restrict__ kbf,
               const short* __restrict__ vt,
               const float* __restrict__ a_ws, const float* __restrict__ M_ws,
               const float* __restrict__ c_ws, const float* __restrict__ onw,
               float* __restrict__ num_ws, float* __restrict__ den_ws,
               float* __restrict__ out) {
    __shared__ __align__(16) char LDSb[73728];

    const int bid = blockIdx.x;
    const int seq = bid & 7;
    const int local = bid >> 3;
    int qt, kt0, kt1, pq;
    bool direct;
    if (local < 32) {
        qt = 31 - (local >> 1);
        int nkt = qt + 1;
        int c0 = (nkt + 1) >> 1;
        if ((local & 1) == 0) { kt0 = 0; kt1 = c0; } else { kt0 = c0; kt1 = nkt; }
        pq = (qt - 16) * 2 + (local & 1);
        direct = false;
    } else {
        qt = 47 - local;
        kt0 = 0; kt1 = qt + 1;
        pq = 0;
        direct = true;
    }

    const int tid = threadIdx.x;
    const int w  = tid >> 6;
    const int rg = w & 1;
    const int ct = w >> 1;
    const int l  = tid & 63;
    const int l31 = l & 31;
    const int h5  = l >> 5;
    const int h = seq & 3;
    const int b = seq >> 2;

    const long seqbase = (long)seq * S_ * DH_;
    const long gbase = (long)seq * S_;
    const int i0 = qt * 64;

    const char* kseq = (const char*)(kbf + seqbase);
    const char* vseq = (const char*)(vt + seqbase);

    int preK[8], preV[8];
#pragma unroll
    for (int i = 0; i < 8; i++) {
        int r = w * 16 + i * 2 + (l >> 5);
        preK[i] = r * 512 + ((l31 * 16) ^ ((r & 31) << 4));      // 32-slot swizzle
        int d = w * 64 + i * 8 + (l >> 3);
        preV[i] = d * (S_ * 2) + (((l & 7) * 16) ^ ((d & 7) << 4));
    }

    float Mi[16], ci[16];
#pragma unroll
    for (int reg = 0; reg < 16; reg++) {
        int rowL = 32 * rg + (reg & 3) + 8 * (reg >> 2) + 4 * h5;
        Mi[reg] = M_ws[gbase + i0 + rowL];
        ci[reg] = c_ws[gbase + i0 + rowL];
    }

    // ---- stage Q through K region (32-slot swizzle), pull A-frags
#pragma unroll
    for (int rep = 0; rep < 8; rep++) {
        int idx = tid + rep * 256;
        int r = idx >> 5, c = idx & 31;
        s16x8 val = *(const s16x8*)(qbf + seqbase + (long)(i0 + r) * DH_ + c * 8);
        int byte = (r * 512) + ((c * 16) ^ ((r & 31) << 4));
        *(s16x8*)(LDSb + byte) = val;
    }
    __syncthreads();
    bf16x8 qfrag[16];
    {
        int qrow = 32 * rg + l31;
        int qswz = (qrow & 31) << 4;
#pragma unroll
        for (int dc = 0; dc < 16; dc++)
            qfrag[dc] = *(const bf16x8*)(LDSb + (qrow * 512 + ((dc * 32 + h5 * 16) ^ qswz)));
    }
    __syncthreads();

    f32x16 oacc[4] = {};
    float denacc[16] = {};

    const char* Klds  = LDSb;
    const char* Vtlds = LDSb + 32768;
    char* Plds = LDSb + 65536;

    for (int kt = kt0; kt < kt1; kt++) {
        const int j0 = kt * 64;
        {
            const char* ks = kseq + (long)j0 * 512;
            const char* vs = vseq + (long)j0 * 2;
            char* kd = LDSb + w * 8192;
            char* vd = LDSb + 32768 + w * 8192;
#pragma unroll
            for (int i = 0; i < 8; i++) gload16(ks + preK[i], kd + i * 1024);
#pragma unroll
            for (int i = 0; i < 8; i++) gload16(vs + preV[i], vd + i * 1024);
        }
        float aj = a_ws[gbase + j0 + 32 * ct + l31];
        __syncthreads();

        // ---- QK^T (conflict-free K reads)
        f32x16 sacc = {};
        {
            int j = 32 * ct + l31;
            int jswz = (j & 31) << 4;
            int jbase = j * 512;
            __builtin_amdgcn_s_setprio(1);
#pragma unroll
            for (int dc = 0; dc < 16; dc++) {
                bf16x8 kf = *(const bf16x8*)(Klds + (jbase + ((dc * 32 + h5 * 16) ^ jswz)));
                sacc = __builtin_amdgcn_mfma_f32_32x32x16_bf16(qfrag[dc], kf, sacc, 0, 0, 0);
            }
            __builtin_amdgcn_s_setprio(0);
        }
        // ---- P
        {
            int jg = j0 + 32 * ct + l31;
#pragma unroll
            for (int reg = 0; reg < 16; reg++) {
                int rowL = 32 * rg + (reg & 3) + 8 * (reg >> 2) + 4 * h5;
                float p = sacc[reg] * 0.0625f * __expf(aj - Mi[reg]);
                if (jg > i0 + rowL) p = 0.f;
                denacc[reg] += p;
                int byte = (rowL * 128 + (32 * ct + l31) * 2) ^ ((rowL & 7) << 4);
                *(short*)(Plds + byte) = f2bf(p);
            }
        }
        __syncthreads();

        // ---- PV
        bf16x8 pfrag[4];
        {
            int prow = 32 * rg + l31;
            int pswz = (prow & 7) << 4;
#pragma unroll
            for (int k4 = 0; k4 < 4; k4++)
                pfrag[k4] = *(const bf16x8*)(Plds + ((prow * 128 + k4 * 32 + h5 * 16) ^ pswz));
        }
        __builtin_amdgcn_s_setprio(1);
#pragma unroll
        for (int dt = 0; dt < 4; dt++) {
            int d = 128 * ct + 32 * dt + l31;
            int dbase = d * 128, dswz = (d & 7) << 4;
#pragma unroll
            for (int k4 = 0; k4 < 4; k4++) {
                bf16x8 vf = *(const bf16x8*)(Vtlds + ((dbase + k4 * 32 + h5 * 16) ^ dswz));
                oacc[dt] = __builtin_amdgcn_mfma_f32_32x32x16_bf16(pfrag[k4], vf, oacc[dt], 0, 0, 0);
            }
        }
        __builtin_amdgcn_s_setprio(0);
        __syncthreads();
    }

    // ---- wave-local den reduction
    float dred[16];
#pragma unroll
    for (int reg = 0; reg < 16; reg++) {
        float dsum = denacc[reg];
        dsum += __shfl_xor(dsum, 1);
        dsum += __shfl_xor(dsum, 2);
        dsum += __shfl_xor(dsum, 4);
        dsum += __shfl_xor(dsum, 8);
        dsum += __shfl_xor(dsum, 16);
        dred[reg] = dsum;
    }

    if (!direct) {
        const long cid = (long)pq * 8 + seq;
        const long nbase = cid * 64 * 256;
#pragma unroll
        for (int reg = 0; reg < 16; reg++) {
            int rowL = 32 * rg + (reg & 3) + 8 * (reg >> 2) + 4 * h5;
            if (l31 == 0) den_ws[cid * 128 + ct * 64 + rowL] = dred[reg];
        }
#pragma unroll
        for (int dt = 0; dt < 4; dt++) {
#pragma unroll
            for (int reg = 0; reg < 16; reg++) {
                int rowL = 32 * rg + (reg & 3) + 8 * (reg >> 2) + 4 * h5;
                num_ws[nbase + (long)rowL * 256 + 128 * ct + 32 * dt + l31] = oacc[dt][reg];
            }
        }
        return;
    }

    // ---- direct epilogue: cross-ct den exchange, normalize, two-pass LN, store
    float* fl = (float*)Plds;
#pragma unroll
    for (int reg = 0; reg < 16; reg++) {
        int rowL = 32 * rg + (reg & 3) + 8 * (reg >> 2) + 4 * h5;
        if (l31 == 0) fl[rowL * 2 + ct] = dred[reg];
    }
    __syncthreads();
    float inv[16];
#pragma unroll
    for (int reg = 0; reg < 16; reg++) {
        int rowL = 32 * rg + (reg & 3) + 8 * (reg >> 2) + 4 * h5;
        float den = fl[rowL * 2] + fl[rowL * 2 + 1];
        float lb = __expf(-ci[reg] - Mi[reg]);
        inv[reg] = 1.f / (fmaxf(fabsf(den), lb) + EPSF);
    }
#pragma unroll
    for (int reg = 0; reg < 16; reg++) {
        float s = 0.f;
#pragma unroll
        for (int dt = 0; dt < 4; dt++) { oacc[dt][reg] *= inv[reg]; s += oacc[dt][reg]; }
        s += __shfl_xor(s, 1); s += __shfl_xor(s, 2); s += __shfl_xor(s, 4);
        s += __shfl_xor(s, 8); s += __shfl_xor(s, 16);
        int rowL = 32 * rg + (reg & 3) + 8 * (reg >> 2) + 4 * h5;
        if (l31 == 0) fl[128 + rowL * 2 + ct] = s;
    }
    __syncthreads();
    float mean[16];
#pragma unroll
    for (int reg = 0; reg < 16; reg++) {
        int rowL = 32 * rg + (reg & 3) + 8 * (reg >> 2) + 4 * h5;
        mean[reg] = (fl[128 + rowL * 2] + fl[128 + rowL * 2 + 1]) * (1.f / 256.f);
    }
#pragma unroll
    for (int reg = 0; reg < 16; reg++) {
        float vs = 0.f;
#pragma unroll
        for (int dt = 0; dt < 4; dt++) { float dx = oacc[dt][reg] - mean[reg]; vs += dx * dx; }
        vs += __shfl_xor(vs, 1); vs += __shfl_xor(vs, 2); vs += __shfl_xor(vs, 4);
        vs += __shfl_xor(vs, 8); vs += __shfl_xor(vs, 16);
        int rowL = 32 * rg + (reg & 3) + 8 * (reg >> 2) + 4 * h5;
        if (l31 == 0) fl[256 + rowL * 2 + ct] = vs;
    }
    __syncthreads();
#pragma unroll
    for (int dt = 0; dt < 4; dt++) {
        int dcol = 128 * ct + 32 * dt + l31;
        float wv = onw[h * DH_ + dcol];
#pragma unroll
        for (int reg = 0; reg < 16; reg++) {
            int rowL = 32 * rg + (reg & 3) + 8 * (reg >> 2) + 4 * h5;
            float var = (fl[256 + rowL * 2] + fl[256 + rowL * 2 + 1]) * (1.f / 256.f);
            float rstd = rsqrtf(var + EPSF);
            out[((long)b * S_ + i0 + rowL) * E_ + h * DH_ + dcol] =
                (oacc[dt][reg] - mean[reg]) * rstd * wv;
        }
    }
}

// ================= reduce (split tiles qt>=16): 2 chunks + normalizer + LN
// grid 256: seq = bid&7, qh = bid>>3 in [0,32): qt = 16+(qh>>1), half = qh&1
__global__ __launch_bounds__(256)
void reduce_kernel(const float* __restrict__ num_ws, const float* __restrict__ den_ws,
                   const float* __restrict__ c_ws, const float* __restrict__ M_ws,
                   const float* __restrict__ onw, float* __restrict__ out) {
    const int bid = blockIdx.x;
    const int seq = bid & 7;
    const int qh = bid >> 3;
    const int qt = 16 + (qh >> 1);
    const int half = qh & 1;
    const int h = seq & 3;
    const int b = seq >> 2;
    const int w = threadIdx.x >> 6;
    const int l = threadIdx.x & 63;
    const long gbase = (long)seq * S_;
    const long cid0 = (long)((qt - 16) * 2) * 8 + seq;
    const long cid1 = cid0 + 8;

    float4 w4 = *(const float4*)(onw + h * DH_ + l * 4);

    for (int rr = 0; rr < 8; rr++) {
        int row = half * 32 + w * 8 + rr;
        int s = qt * 64 + row;
        const float4 p0 = *(const float4*)(num_ws + cid0 * 16384 + (long)row * 256 + l * 4);
        const float4 p1 = *(const float4*)(num_ws + cid1 * 16384 + (long)row * 256 + l * 4);
        float4 acc = {p0.x + p1.x, p0.y + p1.y, p0.z + p1.z, p0.w + p1.w};
        float dsum = den_ws[cid0 * 128 + row] + den_ws[cid0 * 128 + 64 + row]
                   + den_ws[cid1 * 128 + row] + den_ws[cid1 * 128 + 64 + row];
        float lb = __expf(-c_ws[gbase + s] - M_ws[gbase + s]);
        float inv = 1.f / (fmaxf(fabsf(dsum), lb) + EPSF);
        float4 x = {acc.x * inv, acc.y * inv, acc.z * inv, acc.w * inv};
        float sum = x.x + x.y + x.z + x.w;
        sum += __shfl_xor(sum, 1); sum += __shfl_xor(sum, 2); sum += __shfl_xor(sum, 4);
        sum += __shfl_xor(sum, 8); sum += __shfl_xor(sum, 16); sum += __shfl_xor(sum, 32);
        float mean = sum * (1.f / 256.f);
        float vx = x.x - mean, vy = x.y - mean, vz = x.z - mean, vw = x.w - mean;
        float vs = vx * vx + vy * vy + vz * vz + vw * vw;
        vs += __shfl_xor(vs, 1); vs += __shfl_xor(vs, 2); vs += __shfl_xor(vs, 4);
        vs += __shfl_xor(vs, 8); vs += __shfl_xor(vs, 16); vs += __shfl_xor(vs, 32);
        float rstd = rsqrtf(vs * (1.f / 256.f) + EPSF);
        float4 o;
        o.x = vx * rstd * w4.x; o.y = vy * rstd * w4.y;
        o.z = vz * rstd * w4.z; o.w = vw * rstd * w4.w;
        *(float4*)(out + ((long)b * S_ + s) * E_ + h * DH_ + l * 4) = o;
    }
}

// ================= fallback mono kernel (proven R1 version) if ws too small
__global__ __launch_bounds__(256)
void mlstm_mono(const short* __restrict__ qbf, const short* __restrict__ kbf,
                const short* __restrict__ vt,
                const float* __restrict__ a_ws, const float* __restrict__ M_ws,
                const float* __restrict__ c_ws, const float* __restrict__ onw,
                float* __restrict__ out) {
    __shared__ __align__(16) short Klds[64 * 256];
    __shared__ __align__(16) short Vtlds[256 * 64];
    short* Plds = Klds;

    const int bid = blockIdx.x;
    const int seq = bid & 7;
    const int qt = bid >> 3;
    const int h = seq & 3;
    const int b = seq >> 2;
    const int tid = threadIdx.x;
    const int w = tid >> 6;
    const int l = tid & 63;
    const int l15 = l & 15;
    const int g = l >> 4;

    const long seqbase = (long)seq * S_ * DH_;
    const long gbase = (long)seq * S_;
    const int i0 = qt * 64;

    float Mi_r[4], ci_r[4];
#pragma unroll
    for (int r = 0; r < 4; r++) {
        int il = 16 * w + 4 * g + r;
        Mi_r[r] = M_ws[gbase + i0 + il];
        ci_r[r] = c_ws[gbase + i0 + il];
    }
#pragma unroll
    for (int rep = 0; rep < 8; rep++) {
        int idx = tid + rep * 256;
        int r = idx >> 5, c = idx & 31;
        s16x8 val = *(const s16x8*)(qbf + seqbase + (long)(i0 + r) * DH_ + c * 8);
        int byte = (r * 512 + c * 16) ^ ((r & 7) << 4);
        *(s16x8*)((char*)Klds + byte) = val;
    }
    __syncthreads();
    bf16x8 qfrag[8];
#pragma unroll
    for (int dc = 0; dc < 8; dc++) {
        int r = 16 * w + l15;
        int byte = (r * 512 + (8 * g + 32 * dc) * 2) ^ ((r & 7) << 4);
        qfrag[dc] = *(const bf16x8*)((const char*)Klds + byte);
    }
    __syncthreads();

    const f32x4 fzero = {0.f, 0.f, 0.f, 0.f};
    f32x4 oacc[16];
#pragma unroll
    for (int dt = 0; dt < 16; dt++) oacc[dt] = fzero;
    float den[4] = {0.f, 0.f, 0.f, 0.f};

    const int nkt = qt + 1;
    for (int kt = 0; kt < nkt; kt++) {
        const int j0 = kt * 64;
#pragma unroll
        for (int rep = 0; rep < 8; rep++) {
            int idx = tid + rep * 256;
            int r = idx >> 5, c = idx & 31;
            s16x8 val = *(const s16x8*)(kbf + seqbase + (long)(j0 + r) * DH_ + c * 8);
            int byte = (r * 512 + c * 16) ^ ((r & 7) << 4);
            *(s16x8*)((char*)Klds + byte) = val;
        }
#pragma unroll
        for (int rep = 0; rep < 8; rep++) {
            int idx = tid + rep * 256;
            int d = idx >> 3, c = idx & 7;
            s16x8 val = *(const s16x8*)(vt + seqbase + (long)d * S_ + j0 + c * 8);
            int byte = (d * 128 + c * 16) ^ ((d & 7) << 4);
            *(s16x8*)((char*)Vtlds + byte) = val;
        }
        float aj_ct[4];
#pragma unroll
        for (int ct = 0; ct < 4; ct++) aj_ct[ct] = a_ws[gbase + j0 + 16 * ct + l15];
        __syncthreads();

        f32x4 sacc[4];
#pragma unroll
        for (int ct = 0; ct < 4; ct++) sacc[ct] = fzero;
#pragma unroll
        for (int dc = 0; dc < 8; dc++) {
#pragma unroll
            for (int ct = 0; ct < 4; ct++) {
                int j = 16 * ct + l15;
                int byte = (j * 512 + (8 * g + 32 * dc) * 2) ^ ((j & 7) << 4);
                bf16x8 kf = *(const bf16x8*)((const char*)Klds + byte);
                sacc[ct] = __builtin_amdgcn_mfma_f32_16x16x32_bf16(qfrag[dc], kf, sacc[ct], 0, 0, 0);
            }
        }
        __syncthreads();

        const bool diag = (kt == qt);
#pragma unroll
        for (int ct = 0; ct < 4; ct++) {
            int jl = 16 * ct + l15;
            float aj = aj_ct[ct];
#pragma unroll
            for (int r = 0; r < 4; r++) {
                int il = 16 * w + 4 * g + r;
                float p = sacc[ct][r] * 0.0625f * __expf(aj - Mi_r[r]);
                if (diag && jl > il) p = 0.f;
                den[r] += p;
                int byte = (il * 128 + jl * 2) ^ ((il & 7) << 4);
                *(short*)((char*)Plds + byte) = f2bf(p);
            }
        }
        __syncthreads();

        bf16x8 pfrag[2];
#pragma unroll
        for (int jc = 0; jc < 2; jc++) {
            int i = 16 * w + l15;
            int byte = (i * 128 + (8 * g + 32 * jc) * 2) ^ ((i & 7) << 4);
            pfrag[jc] = *(const bf16x8*)((const char*)Plds + byte);
        }
#pragma unroll
        for (int dt = 0; dt < 16; dt++) {
#pragma unroll
            for (int jc = 0; jc < 2; jc++) {
                int d = 16 * dt + l15;
                int byte = (d * 128 + (8 * g + 32 * jc) * 2) ^ ((d & 7) << 4);
                bf16x8 vf = *(const bf16x8*)((const char*)Vtlds + byte);
                oacc[dt] = __builtin_amdgcn_mfma_f32_16x16x32_bf16(pfrag[jc], vf, oacc[dt], 0, 0, 0);
            }
        }
        __syncthreads();
    }

#pragma unroll
    for (int r = 0; r < 4; r++) {
        float dsum = den[r];
        dsum += __shfl_xor(dsum, 1);
        dsum += __shfl_xor(dsum, 2);
        dsum += __shfl_xor(dsum, 4);
        dsum += __shfl_xor(dsum, 8);
        int il = 16 * w + 4 * g + r;
        float lb = __expf(-ci_r[r] - Mi_r[r]);
        float inv = 1.f / (fmaxf(fabsf(dsum), lb) + EPSF);
        float x[16];
        float sum = 0.f;
#pragma unroll
        for (int dt = 0; dt < 16; dt++) { x[dt] = oacc[dt][r] * inv; sum += x[dt]; }
        sum += __shfl_xor(sum, 1); sum += __shfl_xor(sum, 2);
        sum += __shfl_xor(sum, 4); sum += __shfl_xor(sum, 8);
        float mean = sum * (1.f / 256.f);
        float vs = 0.f;
#pragma unroll
        for (int dt = 0; dt < 16; dt++) { float dx = x[dt] - mean; vs += dx * dx; }
        vs += __shfl_xor(vs, 1); vs += __shfl_xor(vs, 2);
        vs += __shfl_xor(vs, 4); vs += __shfl_xor(vs, 8);
        float rstd = rsqrtf(vs * (1.f / 256.f) + EPSF);
        long orow = ((long)b * S_ + i0 + il) * E_ + h * DH_;
#pragma unroll
        for (int dt = 0; dt < 16; dt++) {
            int d = 16 * dt + l15;
            out[orow + d] = (x[dt] - mean) * rstd * onw[h * DH_ + d];
        }
    }
}

extern "C" void kernel_launch(void* const* d_in, const int* in_sizes, int n_in,
                              void* d_out, int out_size, void* d_ws, size_t ws_size,
                              hipStream_t stream) {
    const float* q   = (const float*)d_in[0];
    const float* k   = (const float*)d_in[1];
    const float* v   = (const float*)d_in[2];
    const float* igk = (const float*)d_in[3];
    const float* igb = (const float*)d_in[4];
    const float* fgk = (const float*)d_in[5];
    const float* fgb = (const float*)d_in[6];
    const float* onw = (const float*)d_in[7];
    float* out = (float*)d_out;

    char* ws = (char*)d_ws;
    float* ig_ws = (float*)(ws);
    float* fg_ws = (float*)(ws + (64  << 10));
    float* c_ws  = (float*)(ws + (128 << 10));
    float* a_ws  = (float*)(ws + (192 << 10));
    float* M_ws  = (float*)(ws + (256 << 10));
    short* qbf   = (short*)(ws + (1L  << 20));
    short* kbf   = (short*)(ws + (9L  << 20));
    short* vtb   = (short*)(ws + (17L << 20));
    float* num_ws = (float*)(ws + (25L << 20));        // 256*64*256*4 = 16 MB
    float* den_ws = (float*)(ws + (60L << 20));        // 256*128*4 = 128 KB

    prep_kernel<<<1536, 256, 0, stream>>>(q, k, v, igk, igb, fgk, fgb,
                                          qbf, kbf, vtb, ig_ws, fg_ws);
    scan_kernel<<<8, 1024, 0, stream>>>(ig_ws, fg_ws, c_ws, a_ws, M_ws);

    if (ws_size >= (61L << 20)) {
        mlstm_sb1   <<<384, 256, 0, stream>>>(qbf, kbf, vtb, a_ws, M_ws, c_ws, onw,
                                              num_ws, den_ws, out);
        reduce_kernel<<<256, 256, 0, stream>>>(num_ws, den_ws, c_ws, M_ws, onw, out);
    } else {
        mlstm_mono  <<<256, 256, 0, stream>>>(qbf, kbf, vtb, a_ws, M_ws, c_ws, onw, out);
    }
}

// Round 16
// 130.828 us; speedup vs baseline: 1.0316x; 1.0316x over previous
//
#include <hip/hip_runtime.h>
#include <hip/hip_bf16.h>
#include <math.h>

#define B_  2
#define S_  2048
#define E_  1024
#define NH_ 4
#define DH_ 256
#define EPSF 1e-6f

typedef __attribute__((ext_vector_type(4)))  short  s16x4;
typedef __attribute__((ext_vector_type(8)))  short  s16x8;
typedef __attribute__((ext_vector_type(8)))  __bf16 bf16x8;
typedef __attribute__((ext_vector_type(4)))  float  f32x4;
typedef __attribute__((ext_vector_type(16))) float  f32x16;

static __device__ __forceinline__ short f2bf(float f) {
    unsigned u = __builtin_bit_cast(unsigned, f);
    u = (u + 0x7FFFu + ((u >> 16) & 1u)) >> 16;
    return (short)u;
}

static __device__ __forceinline__ void gload16(const void* g, void* l) {
    __builtin_amdgcn_global_load_lds(
        (__attribute__((address_space(1))) void*)g,
        (__attribute__((address_space(3))) void*)l, 16, 0, 0);
}

// ---------------- prep: fused convert(q,k)+gates [0..511] and v-transpose [512..1535]
__global__ __launch_bounds__(256)
void prep_kernel(const float* __restrict__ q, const float* __restrict__ k,
                 const float* __restrict__ v,
                 const float* __restrict__ igk, const float* __restrict__ igb,
                 const float* __restrict__ fgk, const float* __restrict__ fgb,
                 short* __restrict__ qbf, short* __restrict__ kbf,
                 short* __restrict__ vt,
                 float* __restrict__ ig_ws, float* __restrict__ fg_ws) {
    const int bid = blockIdx.x;
    if (bid < 512) {
        int wid = threadIdx.x >> 6, lane = threadIdx.x & 63;
        int row0 = (bid * 4 + wid) * 2;
        int b = row0 >> 11;
        int s0 = row0 & 2047;
        float accI[2][4] = {};
        float accF[2][4] = {};
        const float* srcs[3] = {q, k, v};
        short* dsts[2] = {qbf, kbf};
#pragma unroll
        for (int p = 0; p < 3; p++) {
            const float* src = srcs[p] + ((long)b * S_ + s0) * E_;
#pragma unroll
            for (int c = 0; c < 4; c++) {
                int e = c * 256 + lane * 4;
                float4 x0 = *(const float4*)(src + e);
                float4 x1 = *(const float4*)(src + E_ + e);
                if (p < 2) {
                    s16x4 o0, o1;
                    o0[0] = f2bf(x0.x); o0[1] = f2bf(x0.y); o0[2] = f2bf(x0.z); o0[3] = f2bf(x0.w);
                    o1[0] = f2bf(x1.x); o1[1] = f2bf(x1.y); o1[2] = f2bf(x1.z); o1[3] = f2bf(x1.w);
                    long db = ((long)(b * NH_ + c) * S_ + s0) * DH_ + lane * 4;
                    *(s16x4*)(dsts[p] + db) = o0;
                    *(s16x4*)(dsts[p] + db + DH_) = o1;
                }
                const float4* wi = (const float4*)(igk + (long)(p * E_ + e) * 4);
                const float4* wf = (const float4*)(fgk + (long)(p * E_ + e) * 4);
                float xs0[4] = {x0.x, x0.y, x0.z, x0.w};
                float xs1[4] = {x1.x, x1.y, x1.z, x1.w};
#pragma unroll
                for (int j = 0; j < 4; j++) {
                    float4 wij = wi[j], wfj = wf[j];
                    accI[0][0] += xs0[j] * wij.x; accI[0][1] += xs0[j] * wij.y;
                    accI[0][2] += xs0[j] * wij.z; accI[0][3] += xs0[j] * wij.w;
                    accF[0][0] += xs0[j] * wfj.x; accF[0][1] += xs0[j] * wfj.y;
                    accF[0][2] += xs0[j] * wfj.z; accF[0][3] += xs0[j] * wfj.w;
                    accI[1][0] += xs1[j] * wij.x; accI[1][1] += xs1[j] * wij.y;
                    accI[1][2] += xs1[j] * wij.z; accI[1][3] += xs1[j] * wij.w;
                    accF[1][0] += xs1[j] * wfj.x; accF[1][1] += xs1[j] * wfj.y;
                    accF[1][2] += xs1[j] * wfj.z; accF[1][3] += xs1[j] * wfj.w;
                }
            }
        }
#pragma unroll
        for (int r = 0; r < 2; r++) {
#pragma unroll
            for (int hh = 0; hh < 4; hh++) {
                float aI = accI[r][hh], aF = accF[r][hh];
                for (int m = 1; m < 64; m <<= 1) { aI += __shfl_xor(aI, m); aF += __shfl_xor(aF, m); }
                if (lane == 0) {
                    ig_ws[((long)(b * NH_ + hh)) * S_ + s0 + r] = aI + igb[hh];
                    fg_ws[((long)(b * NH_ + hh)) * S_ + s0 + r] = aF + fgb[hh];
                }
            }
        }
    } else {
        __shared__ short tile[64][66];
        int b2 = bid - 512;
        int dt = b2 & 3, st = (b2 >> 2) & 31, hh = (b2 >> 7) & 3, b = b2 >> 9;
        int t = threadIdx.x;
#pragma unroll
        for (int rep = 0; rep < 16; rep++) {
            int idx = t + rep * 256;
            int ts = idx >> 6, td = idx & 63;
            float x = v[((long)b * S_ + st * 64 + ts) * E_ + hh * DH_ + dt * 64 + td];
            tile[ts][td] = f2bf(x);
        }
        __syncthreads();
        long obase = ((long)(b * NH_ + hh) * DH_ + dt * 64) * S_ + st * 64;
#pragma unroll
        for (int rep = 0; rep < 8; rep++) {
            int idx = t + rep * 256;
            int dd = idx >> 5, sp = (idx & 31) * 2;
            short2 val;
            val.x = tile[sp][dd];
            val.y = tile[sp + 1][dd];
            *(short2*)(vt + obase + (long)dd * S_ + sp) = val;
        }
    }
}

// ---------------- scan: 1024 threads/seq -> 2 serial chunks
__global__ __launch_bounds__(1024)
void scan_kernel(const float* __restrict__ ig_ws, const float* __restrict__ fg_ws,
                 float* __restrict__ c_ws, float* __restrict__ a_ws,
                 float* __restrict__ M_ws) {
    __shared__ float wsum[16], wmax[16];
    int seq = blockIdx.x;
    int tid = threadIdx.x, w = tid >> 6, lane = tid & 63;
    long base = (long)seq * S_;
    float carryC = 0.f, carryM = -INFINITY;
    for (int ch = 0; ch < S_ / 1024; ch++) {
        int s = ch * 1024 + tid;
        float fgv = fg_ws[base + s];
        float lf = (fgv > 0.f) ? -log1pf(expf(-fgv)) : (fgv - log1pf(expf(fgv)));
        float x = lf;
        for (int d = 1; d < 64; d <<= 1) { float t = __shfl_up(x, d); if (lane >= d) x += t; }
        if (lane == 63) wsum[w] = x;
        __syncthreads();
        float pre = carryC;
        for (int j = 0; j < w; j++) pre += wsum[j];
        float c = pre + x;
        float a = ig_ws[base + s] - c;
        float m = a;
        for (int d = 1; d < 64; d <<= 1) { float t = __shfl_up(m, d); if (lane >= d) m = fmaxf(m, t); }
        if (lane == 63) wmax[w] = m;
        __syncthreads();
        float prem = carryM;
        for (int j = 0; j < w; j++) prem = fmaxf(prem, wmax[j]);
        float M = fmaxf(prem, m);
        c_ws[base + s] = c;
        a_ws[base + s] = a;
        M_ws[base + s] = M;
        float allsum = 0.f, allmax = -INFINITY;
        for (int j = 0; j < 16; j++) { allsum += wsum[j]; allmax = fmaxf(allmax, wmax[j]); }
        carryC += allsum;
        carryM = fmaxf(carryM, allmax);
        __syncthreads();
    }
}

// ================= split-K main (R11 loop verbatim) + in-block epilogue for nc==1.
// grid 384: seq = bid&7, local = bid>>3 in [0,48):
//   local <32: split qt = 31-(local>>1), chunk = local&1, pq=(qt-16)*2+chunk
//   local>=32: direct qt = 47-local, full range, epilogue in-block -> out
// LDS 72KB: K 32K | V 32K | P 8K (P reused as f32 scratch in epilogue)
__global__ __launch_bounds__(256)
void mlstm_sb1(const short* __restrict__ qbf, const short* __restrict__ kbf,
               const short* __restrict__ vt,
               const float* __restrict__ a_ws, const float* __restrict__ M_ws,
               const float* __restrict__ c_ws, const float* __restrict__ onw,
               float* __restrict__ num_ws, float* __restrict__ den_ws,
               float* __restrict__ out) {
    __shared__ __align__(16) char LDSb[73728];

    const int bid = blockIdx.x;
    const int seq = bid & 7;
    const int local = bid >> 3;
    int qt, kt0, kt1, pq;
    bool direct;
    if (local < 32) {
        qt = 31 - (local >> 1);
        int nkt = qt + 1;
        int c0 = (nkt + 1) >> 1;
        if ((local & 1) == 0) { kt0 = 0; kt1 = c0; } else { kt0 = c0; kt1 = nkt; }
        pq = (qt - 16) * 2 + (local & 1);
        direct = false;
    } else {
        qt = 47 - local;
        kt0 = 0; kt1 = qt + 1;
        pq = 0;
        direct = true;
    }

    const int tid = threadIdx.x;
    const int w  = tid >> 6;
    const int rg = w & 1;
    const int ct = w >> 1;
    const int l  = tid & 63;
    const int l31 = l & 31;
    const int h5  = l >> 5;
    const int h = seq & 3;
    const int b = seq >> 2;

    const long seqbase = (long)seq * S_ * DH_;
    const long gbase = (long)seq * S_;
    const int i0 = qt * 64;

    const char* kseq = (const char*)(kbf + seqbase);
    const char* vseq = (const char*)(vt + seqbase);

    int preK[8], preV[8];
#pragma unroll
    for (int i = 0; i < 8; i++) {
        int r = w * 16 + i * 2 + (l >> 5);
        preK[i] = r * 512 + (((l & 31) * 16) ^ ((r & 7) << 4));
        int d = w * 64 + i * 8 + (l >> 3);
        preV[i] = d * (S_ * 2) + (((l & 7) * 16) ^ ((d & 7) << 4));
    }

    float Mi[16], ci[16];
#pragma unroll
    for (int reg = 0; reg < 16; reg++) {
        int rowL = 32 * rg + (reg & 3) + 8 * (reg >> 2) + 4 * h5;
        Mi[reg] = M_ws[gbase + i0 + rowL];
        ci[reg] = c_ws[gbase + i0 + rowL];
    }

    // ---- stage Q through K region, pull A-frags
#pragma unroll
    for (int rep = 0; rep < 8; rep++) {
        int idx = tid + rep * 256;
        int r = idx >> 5, c = idx & 31;
        s16x8 val = *(const s16x8*)(qbf + seqbase + (long)(i0 + r) * DH_ + c * 8);
        int byte = (r * 512 + c * 16) ^ ((r & 7) << 4);
        *(s16x8*)(LDSb + byte) = val;
    }
    __syncthreads();
    bf16x8 qfrag[16];
    {
        int qrow = 32 * rg + l31;
        int qswz = (qrow & 7) << 4;
#pragma unroll
        for (int dc = 0; dc < 16; dc++)
            qfrag[dc] = *(const bf16x8*)(LDSb + ((qrow * 512 + dc * 32 + h5 * 16) ^ qswz));
    }
    __syncthreads();

    f32x16 oacc[4] = {};
    float denacc[16] = {};

    const char* Klds  = LDSb;
    const char* Vtlds = LDSb + 32768;
    char* Plds = LDSb + 65536;

    for (int kt = kt0; kt < kt1; kt++) {
        const int j0 = kt * 64;
        {
            const char* ks = kseq + (long)j0 * 512;
            const char* vs = vseq + (long)j0 * 2;
            char* kd = LDSb + w * 8192;
            char* vd = LDSb + 32768 + w * 8192;
#pragma unroll
            for (int i = 0; i < 8; i++) gload16(ks + preK[i], kd + i * 1024);
#pragma unroll
            for (int i = 0; i < 8; i++) gload16(vs + preV[i], vd + i * 1024);
        }
        float aj = a_ws[gbase + j0 + 32 * ct + l31];
        __syncthreads();

        // ---- QK^T
        f32x16 sacc = {};
        {
            int j = 32 * ct + l31;
            int jswz = (j & 7) << 4;
            int jbase = j * 512;
#pragma unroll
            for (int dc = 0; dc < 16; dc++) {
                bf16x8 kf = *(const bf16x8*)(Klds + ((jbase + dc * 32 + h5 * 16) ^ jswz));
                sacc = __builtin_amdgcn_mfma_f32_32x32x16_bf16(qfrag[dc], kf, sacc, 0, 0, 0);
            }
        }
        // ---- P
        {
            int jg = j0 + 32 * ct + l31;
#pragma unroll
            for (int reg = 0; reg < 16; reg++) {
                int rowL = 32 * rg + (reg & 3) + 8 * (reg >> 2) + 4 * h5;
                float p = sacc[reg] * 0.0625f * __expf(aj - Mi[reg]);
                if (jg > i0 + rowL) p = 0.f;
                denacc[reg] += p;
                int byte = (rowL * 128 + (32 * ct + l31) * 2) ^ ((rowL & 7) << 4);
                *(short*)(Plds + byte) = f2bf(p);
            }
        }
        __syncthreads();

        // ---- PV
        bf16x8 pfrag[4];
        {
            int prow = 32 * rg + l31;
            int pswz = (prow & 7) << 4;
#pragma unroll
            for (int k4 = 0; k4 < 4; k4++)
                pfrag[k4] = *(const bf16x8*)(Plds + ((prow * 128 + k4 * 32 + h5 * 16) ^ pswz));
        }
#pragma unroll
        for (int dt = 0; dt < 4; dt++) {
            int d = 128 * ct + 32 * dt + l31;
            int dbase = d * 128, dswz = (d & 7) << 4;
#pragma unroll
            for (int k4 = 0; k4 < 4; k4++) {
                bf16x8 vf = *(const bf16x8*)(Vtlds + ((dbase + k4 * 32 + h5 * 16) ^ dswz));
                oacc[dt] = __builtin_amdgcn_mfma_f32_32x32x16_bf16(pfrag[k4], vf, oacc[dt], 0, 0, 0);
            }
        }
        __syncthreads();
    }

    // ---- wave-local den reduction (over l31; both halves of each 32-group hold it)
    float dred[16];
#pragma unroll
    for (int reg = 0; reg < 16; reg++) {
        float dsum = denacc[reg];
        dsum += __shfl_xor(dsum, 1);
        dsum += __shfl_xor(dsum, 2);
        dsum += __shfl_xor(dsum, 4);
        dsum += __shfl_xor(dsum, 8);
        dsum += __shfl_xor(dsum, 16);
        dred[reg] = dsum;
    }

    if (!direct) {
        // ---- write partials (num layout identical to R11)
        const long cid = (long)pq * 8 + seq;
        const long nbase = cid * 64 * 256;
#pragma unroll
        for (int reg = 0; reg < 16; reg++) {
            int rowL = 32 * rg + (reg & 3) + 8 * (reg >> 2) + 4 * h5;
            if (l31 == 0) den_ws[cid * 128 + ct * 64 + rowL] = dred[reg];
        }
#pragma unroll
        for (int dt = 0; dt < 4; dt++) {
#pragma unroll
            for (int reg = 0; reg < 16; reg++) {
                int rowL = 32 * rg + (reg & 3) + 8 * (reg >> 2) + 4 * h5;
                num_ws[nbase + (long)rowL * 256 + 128 * ct + 32 * dt + l31] = oacc[dt][reg];
            }
        }
        return;
    }

    // ---- direct epilogue: cross-ct den exchange, normalize, two-pass LN, store
    float* fl = (float*)Plds;               // [0,128): den, [128,256): sum, [256,384): sumsq
#pragma unroll
    for (int reg = 0; reg < 16; reg++) {
        int rowL = 32 * rg + (reg & 3) + 8 * (reg >> 2) + 4 * h5;
        if (l31 == 0) fl[rowL * 2 + ct] = dred[reg];
    }
    __syncthreads();
    float inv[16];
#pragma unroll
    for (int reg = 0; reg < 16; reg++) {
        int rowL = 32 * rg + (reg & 3) + 8 * (reg >> 2) + 4 * h5;
        float den = fl[rowL * 2] + fl[rowL * 2 + 1];
        float lb = __expf(-ci[reg] - Mi[reg]);
        inv[reg] = 1.f / (fmaxf(fabsf(den), lb) + EPSF);
    }
    // x = oacc*inv; row sums
#pragma unroll
    for (int reg = 0; reg < 16; reg++) {
        float s = 0.f;
#pragma unroll
        for (int dt = 0; dt < 4; dt++) { oacc[dt][reg] *= inv[reg]; s += oacc[dt][reg]; }
        s += __shfl_xor(s, 1); s += __shfl_xor(s, 2); s += __shfl_xor(s, 4);
        s += __shfl_xor(s, 8); s += __shfl_xor(s, 16);
        int rowL = 32 * rg + (reg & 3) + 8 * (reg >> 2) + 4 * h5;
        if (l31 == 0) fl[128 + rowL * 2 + ct] = s;
    }
    __syncthreads();
    float mean[16];
#pragma unroll
    for (int reg = 0; reg < 16; reg++) {
        int rowL = 32 * rg + (reg & 3) + 8 * (reg >> 2) + 4 * h5;
        mean[reg] = (fl[128 + rowL * 2] + fl[128 + rowL * 2 + 1]) * (1.f / 256.f);
    }
#pragma unroll
    for (int reg = 0; reg < 16; reg++) {
        float vs = 0.f;
#pragma unroll
        for (int dt = 0; dt < 4; dt++) { float dx = oacc[dt][reg] - mean[reg]; vs += dx * dx; }
        vs += __shfl_xor(vs, 1); vs += __shfl_xor(vs, 2); vs += __shfl_xor(vs, 4);
        vs += __shfl_xor(vs, 8); vs += __shfl_xor(vs, 16);
        int rowL = 32 * rg + (reg & 3) + 8 * (reg >> 2) + 4 * h5;
        if (l31 == 0) fl[256 + rowL * 2 + ct] = vs;
    }
    __syncthreads();
#pragma unroll
    for (int dt = 0; dt < 4; dt++) {
        int dcol = 128 * ct + 32 * dt + l31;
        float wv = onw[h * DH_ + dcol];
#pragma unroll
        for (int reg = 0; reg < 16; reg++) {
            int rowL = 32 * rg + (reg & 3) + 8 * (reg >> 2) + 4 * h5;
            float var = (fl[256 + rowL * 2] + fl[256 + rowL * 2 + 1]) * (1.f / 256.f);
            float rstd = rsqrtf(var + EPSF);
            out[((long)b * S_ + i0 + rowL) * E_ + h * DH_ + dcol] =
                (oacc[dt][reg] - mean[reg]) * rstd * wv;
        }
    }
}

// ================= reduce (split tiles qt>=16 only): 2 chunks + normalizer + LN
// grid 256: seq = bid&7, qh = bid>>3 in [0,32): qt = 16+(qh>>1), half = qh&1
__global__ __launch_bounds__(256)
void reduce_kernel(const float* __restrict__ num_ws, const float* __restrict__ den_ws,
                   const float* __restrict__ c_ws, const float* __restrict__ M_ws,
                   const float* __restrict__ onw, float* __restrict__ out) {
    const int bid = blockIdx.x;
    const int seq = bid & 7;
    const int qh = bid >> 3;
    const int qt = 16 + (qh >> 1);
    const int half = qh & 1;
    const int h = seq & 3;
    const int b = seq >> 2;
    const int w = threadIdx.x >> 6;
    const int l = threadIdx.x & 63;
    const long gbase = (long)seq * S_;
    const long cid0 = (long)((qt - 16) * 2) * 8 + seq;
    const long cid1 = cid0 + 8;

    float4 w4 = *(const float4*)(onw + h * DH_ + l * 4);

    for (int rr = 0; rr < 8; rr++) {
        int row = half * 32 + w * 8 + rr;
        int s = qt * 64 + row;
        const float4 p0 = *(const float4*)(num_ws + cid0 * 16384 + (long)row * 256 + l * 4);
        const float4 p1 = *(const float4*)(num_ws + cid1 * 16384 + (long)row * 256 + l * 4);
        float4 acc = {p0.x + p1.x, p0.y + p1.y, p0.z + p1.z, p0.w + p1.w};
        float dsum = den_ws[cid0 * 128 + row] + den_ws[cid0 * 128 + 64 + row]
                   + den_ws[cid1 * 128 + row] + den_ws[cid1 * 128 + 64 + row];
        float lb = __expf(-c_ws[gbase + s] - M_ws[gbase + s]);
        float inv = 1.f / (fmaxf(fabsf(dsum), lb) + EPSF);
        float4 x = {acc.x * inv, acc.y * inv, acc.z * inv, acc.w * inv};
        float sum = x.x + x.y + x.z + x.w;
        sum += __shfl_xor(sum, 1); sum += __shfl_xor(sum, 2); sum += __shfl_xor(sum, 4);
        sum += __shfl_xor(sum, 8); sum += __shfl_xor(sum, 16); sum += __shfl_xor(sum, 32);
        float mean = sum * (1.f / 256.f);
        float vx = x.x - mean, vy = x.y - mean, vz = x.z - mean, vw = x.w - mean;
        float vs = vx * vx + vy * vy + vz * vz + vw * vw;
        vs += __shfl_xor(vs, 1); vs += __shfl_xor(vs, 2); vs += __shfl_xor(vs, 4);
        vs += __shfl_xor(vs, 8); vs += __shfl_xor(vs, 16); vs += __shfl_xor(vs, 32);
        float rstd = rsqrtf(vs * (1.f / 256.f) + EPSF);
        float4 o;
        o.x = vx * rstd * w4.x; o.y = vy * rstd * w4.y;
        o.z = vz * rstd * w4.z; o.w = vw * rstd * w4.w;
        *(float4*)(out + ((long)b * S_ + s) * E_ + h * DH_ + l * 4) = o;
    }
}

// ================= fallback mono kernel (proven R1 version) if ws too small
__global__ __launch_bounds__(256)
void mlstm_mono(const short* __restrict__ qbf, const short* __restrict__ kbf,
                const short* __restrict__ vt,
                const float* __restrict__ a_ws, const float* __restrict__ M_ws,
                const float* __restrict__ c_ws, const float* __restrict__ onw,
                float* __restrict__ out) {
    __shared__ __align__(16) short Klds[64 * 256];
    __shared__ __align__(16) short Vtlds[256 * 64];
    short* Plds = Klds;

    const int bid = blockIdx.x;
    const int seq = bid & 7;
    const int qt = bid >> 3;
    const int h = seq & 3;
    const int b = seq >> 2;
    const int tid = threadIdx.x;
    const int w = tid >> 6;
    const int l = tid & 63;
    const int l15 = l & 15;
    const int g = l >> 4;

    const long seqbase = (long)seq * S_ * DH_;
    const long gbase = (long)seq * S_;
    const int i0 = qt * 64;

    float Mi_r[4], ci_r[4];
#pragma unroll
    for (int r = 0; r < 4; r++) {
        int il = 16 * w + 4 * g + r;
        Mi_r[r] = M_ws[gbase + i0 + il];
        ci_r[r] = c_ws[gbase + i0 + il];
    }
#pragma unroll
    for (int rep = 0; rep < 8; rep++) {
        int idx = tid + rep * 256;
        int r = idx >> 5, c = idx & 31;
        s16x8 val = *(const s16x8*)(qbf + seqbase + (long)(i0 + r) * DH_ + c * 8);
        int byte = (r * 512 + c * 16) ^ ((r & 7) << 4);
        *(s16x8*)((char*)Klds + byte) = val;
    }
    __syncthreads();
    bf16x8 qfrag[8];
#pragma unroll
    for (int dc = 0; dc < 8; dc++) {
        int r = 16 * w + l15;
        int byte = (r * 512 + (8 * g + 32 * dc) * 2) ^ ((r & 7) << 4);
        qfrag[dc] = *(const bf16x8*)((const char*)Klds + byte);
    }
    __syncthreads();

    const f32x4 fzero = {0.f, 0.f, 0.f, 0.f};
    f32x4 oacc[16];
#pragma unroll
    for (int dt = 0; dt < 16; dt++) oacc[dt] = fzero;
    float den[4] = {0.f, 0.f, 0.f, 0.f};

    const int nkt = qt + 1;
    for (int kt = 0; kt < nkt; kt++) {
        const int j0 = kt * 64;
#pragma unroll
        for (int rep = 0; rep < 8; rep++) {
            int idx = tid + rep * 256;
            int r = idx >> 5, c = idx & 31;
            s16x8 val = *(const s16x8*)(kbf + seqbase + (long)(j0 + r) * DH_ + c * 8);
            int byte = (r * 512 + c * 16) ^ ((r & 7) << 4);
            *(s16x8*)((char*)Klds + byte) = val;
        }
#pragma unroll
        for (int rep = 0; rep < 8; rep++) {
            int idx = tid + rep * 256;
            int d = idx >> 3, c = idx & 7;
            s16x8 val = *(const s16x8*)(vt + seqbase + (long)d * S_ + j0 + c * 8);
            int byte = (d * 128 + c * 16) ^ ((d & 7) << 4);
            *(s16x8*)((char*)Vtlds + byte) = val;
        }
        float aj_ct[4];
#pragma unroll
        for (int ct = 0; ct < 4; ct++) aj_ct[ct] = a_ws[gbase + j0 + 16 * ct + l15];
        __syncthreads();

        f32x4 sacc[4];
#pragma unroll
        for (int ct = 0; ct < 4; ct++) sacc[ct] = fzero;
#pragma unroll
        for (int dc = 0; dc < 8; dc++) {
#pragma unroll
            for (int ct = 0; ct < 4; ct++) {
                int j = 16 * ct + l15;
                int byte = (j * 512 + (8 * g + 32 * dc) * 2) ^ ((j & 7) << 4);
                bf16x8 kf = *(const bf16x8*)((const char*)Klds + byte);
                sacc[ct] = __builtin_amdgcn_mfma_f32_16x16x32_bf16(qfrag[dc], kf, sacc[ct], 0, 0, 0);
            }
        }
        __syncthreads();

        const bool diag = (kt == qt);
#pragma unroll
        for (int ct = 0; ct < 4; ct++) {
            int jl = 16 * ct + l15;
            float aj = aj_ct[ct];
#pragma unroll
            for (int r = 0; r < 4; r++) {
                int il = 16 * w + 4 * g + r;
                float p = sacc[ct][r] * 0.0625f * __expf(aj - Mi_r[r]);
                if (diag && jl > il) p = 0.f;
                den[r] += p;
                int byte = (il * 128 + jl * 2) ^ ((il & 7) << 4);
                *(short*)((char*)Plds + byte) = f2bf(p);
            }
        }
        __syncthreads();

        bf16x8 pfrag[2];
#pragma unroll
        for (int jc = 0; jc < 2; jc++) {
            int i = 16 * w + l15;
            int byte = (i * 128 + (8 * g + 32 * jc) * 2) ^ ((i & 7) << 4);
            pfrag[jc] = *(const bf16x8*)((const char*)Plds + byte);
        }
#pragma unroll
        for (int dt = 0; dt < 16; dt++) {
#pragma unroll
            for (int jc = 0; jc < 2; jc++) {
                int d = 16 * dt + l15;
                int byte = (d * 128 + (8 * g + 32 * jc) * 2) ^ ((d & 7) << 4);
                bf16x8 vf = *(const bf16x8*)((const char*)Vtlds + byte);
                oacc[dt] = __builtin_amdgcn_mfma_f32_16x16x32_bf16(pfrag[jc], vf, oacc[dt], 0, 0, 0);
            }
        }
        __syncthreads();
    }

#pragma unroll
    for (int r = 0; r < 4; r++) {
        float dsum = den[r];
        dsum += __shfl_xor(dsum, 1);
        dsum += __shfl_xor(dsum, 2);
        dsum += __shfl_xor(dsum, 4);
        dsum += __shfl_xor(dsum, 8);
        int il = 16 * w + 4 * g + r;
        float lb = __expf(-ci_r[r] - Mi_r[r]);
        float inv = 1.f / (fmaxf(fabsf(dsum), lb) + EPSF);
        float x[16];
        float sum = 0.f;
#pragma unroll
        for (int dt = 0; dt < 16; dt++) { x[dt] = oacc[dt][r] * inv; sum += x[dt]; }
        sum += __shfl_xor(sum, 1); sum += __shfl_xor(sum, 2);
        sum += __shfl_xor(sum, 4); sum += __shfl_xor(sum, 8);
        float mean = sum * (1.f / 256.f);
        float vs = 0.f;
#pragma unroll
        for (int dt = 0; dt < 16; dt++) { float dx = x[dt] - mean; vs += dx * dx; }
        vs += __shfl_xor(vs, 1); vs += __shfl_xor(vs, 2);
        vs += __shfl_xor(vs, 4); vs += __shfl_xor(vs, 8);
        float rstd = rsqrtf(vs * (1.f / 256.f) + EPSF);
        long orow = ((long)b * S_ + i0 + il) * E_ + h * DH_;
#pragma unroll
        for (int dt = 0; dt < 16; dt++) {
            int d = 16 * dt + l15;
            out[orow + d] = (x[dt] - mean) * rstd * onw[h * DH_ + d];
        }
    }
}

extern "C" void kernel_launch(void* const* d_in, const int* in_sizes, int n_in,
                              void* d_out, int out_size, void* d_ws, size_t ws_size,
                              hipStream_t stream) {
    const float* q   = (const float*)d_in[0];
    const float* k   = (const float*)d_in[1];
    const float* v   = (const float*)d_in[2];
    const float* igk = (const float*)d_in[3];
    const float* igb = (const float*)d_in[4];
    const float* fgk = (const float*)d_in[5];
    const float* fgb = (const float*)d_in[6];
    const float* onw = (const float*)d_in[7];
    float* out = (float*)d_out;

    char* ws = (char*)d_ws;
    float* ig_ws = (float*)(ws);
    float* fg_ws = (float*)(ws + (64  << 10));
    float* c_ws  = (float*)(ws + (128 << 10));
    float* a_ws  = (float*)(ws + (192 << 10));
    float* M_ws  = (float*)(ws + (256 << 10));
    short* qbf   = (short*)(ws + (1L  << 20));
    short* kbf   = (short*)(ws + (9L  << 20));
    short* vtb   = (short*)(ws + (17L << 20));
    float* num_ws = (float*)(ws + (25L << 20));        // 256*64*256*4 = 16 MB
    float* den_ws = (float*)(ws + (60L << 20));        // 256*128*4 = 128 KB

    prep_kernel<<<1536, 256, 0, stream>>>(q, k, v, igk, igb, fgk, fgb,
                                          qbf, kbf, vtb, ig_ws, fg_ws);
    scan_kernel<<<8, 1024, 0, stream>>>(ig_ws, fg_ws, c_ws, a_ws, M_ws);

    if (ws_size >= (61L << 20)) {
        mlstm_sb1   <<<384, 256, 0, stream>>>(qbf, kbf, vtb, a_ws, M_ws, c_ws, onw,
                                              num_ws, den_ws, out);
        reduce_kernel<<<256, 256, 0, stream>>>(num_ws, den_ws, c_ws, M_ws, onw, out);
    } else {
        mlstm_mono  <<<256, 256, 0, stream>>>(qbf, kbf, vtb, a_ws, M_ws, c_ws, onw, out);
    }
}

// Round 17
// 130.725 us; speedup vs baseline: 1.0324x; 1.0008x over previous
//
#include <hip/hip_runtime.h>
#include <hip/hip_bf16.h>
#include <math.h>

#define B_  2
#define S_  2048
#define E_  1024
#define NH_ 4
#define DH_ 256
#define EPSF 1e-6f

typedef __attribute__((ext_vector_type(4)))  short  s16x4;
typedef __attribute__((ext_vector_type(8)))  short  s16x8;
typedef __attribute__((ext_vector_type(8)))  __bf16 bf16x8;
typedef __attribute__((ext_vector_type(4)))  float  f32x4;
typedef __attribute__((ext_vector_type(16))) float  f32x16;

static __device__ __forceinline__ short f2bf(float f) {
    unsigned u = __builtin_bit_cast(unsigned, f);
    u = (u + 0x7FFFu + ((u >> 16) & 1u)) >> 16;
    return (short)u;
}

static __device__ __forceinline__ void gload16(const void* g, void* l) {
    __builtin_amdgcn_global_load_lds(
        (__attribute__((address_space(1))) void*)g,
        (__attribute__((address_space(3))) void*)l, 16, 0, 0);
}

// ---------------- prep: fused convert(q,k)+gates [0..511] and v-transpose [512..1535]
__global__ __launch_bounds__(256)
void prep_kernel(const float* __restrict__ q, const float* __restrict__ k,
                 const float* __restrict__ v,
                 const float* __restrict__ igk, const float* __restrict__ igb,
                 const float* __restrict__ fgk, const float* __restrict__ fgb,
                 short* __restrict__ qbf, short* __restrict__ kbf,
                 short* __restrict__ vt,
                 float* __restrict__ ig_ws, float* __restrict__ fg_ws) {
    const int bid = blockIdx.x;
    if (bid < 512) {
        int wid = threadIdx.x >> 6, lane = threadIdx.x & 63;
        int row0 = (bid * 4 + wid) * 2;
        int b = row0 >> 11;
        int s0 = row0 & 2047;
        float accI[2][4] = {};
        float accF[2][4] = {};
        const float* srcs[3] = {q, k, v};
        short* dsts[2] = {qbf, kbf};
#pragma unroll
        for (int p = 0; p < 3; p++) {
            const float* src = srcs[p] + ((long)b * S_ + s0) * E_;
#pragma unroll
            for (int c = 0; c < 4; c++) {
                int e = c * 256 + lane * 4;
                float4 x0 = *(const float4*)(src + e);
                float4 x1 = *(const float4*)(src + E_ + e);
                if (p < 2) {
                    s16x4 o0, o1;
                    o0[0] = f2bf(x0.x); o0[1] = f2bf(x0.y); o0[2] = f2bf(x0.z); o0[3] = f2bf(x0.w);
                    o1[0] = f2bf(x1.x); o1[1] = f2bf(x1.y); o1[2] = f2bf(x1.z); o1[3] = f2bf(x1.w);
                    long db = ((long)(b * NH_ + c) * S_ + s0) * DH_ + lane * 4;
                    *(s16x4*)(dsts[p] + db) = o0;
                    *(s16x4*)(dsts[p] + db + DH_) = o1;
                }
                const float4* wi = (const float4*)(igk + (long)(p * E_ + e) * 4);
                const float4* wf = (const float4*)(fgk + (long)(p * E_ + e) * 4);
                float xs0[4] = {x0.x, x0.y, x0.z, x0.w};
                float xs1[4] = {x1.x, x1.y, x1.z, x1.w};
#pragma unroll
                for (int j = 0; j < 4; j++) {
                    float4 wij = wi[j], wfj = wf[j];
                    accI[0][0] += xs0[j] * wij.x; accI[0][1] += xs0[j] * wij.y;
                    accI[0][2] += xs0[j] * wij.z; accI[0][3] += xs0[j] * wij.w;
                    accF[0][0] += xs0[j] * wfj.x; accF[0][1] += xs0[j] * wfj.y;
                    accF[0][2] += xs0[j] * wfj.z; accF[0][3] += xs0[j] * wfj.w;
                    accI[1][0] += xs1[j] * wij.x; accI[1][1] += xs1[j] * wij.y;
                    accI[1][2] += xs1[j] * wij.z; accI[1][3] += xs1[j] * wij.w;
                    accF[1][0] += xs1[j] * wfj.x; accF[1][1] += xs1[j] * wfj.y;
                    accF[1][2] += xs1[j] * wfj.z; accF[1][3] += xs1[j] * wfj.w;
                }
            }
        }
#pragma unroll
        for (int r = 0; r < 2; r++) {
#pragma unroll
            for (int hh = 0; hh < 4; hh++) {
                float aI = accI[r][hh], aF = accF[r][hh];
                for (int m = 1; m < 64; m <<= 1) { aI += __shfl_xor(aI, m); aF += __shfl_xor(aF, m); }
                if (lane == 0) {
                    ig_ws[((long)(b * NH_ + hh)) * S_ + s0 + r] = aI + igb[hh];
                    fg_ws[((long)(b * NH_ + hh)) * S_ + s0 + r] = aF + fgb[hh];
                }
            }
        }
    } else {
        __shared__ short tile[64][66];
        int b2 = bid - 512;
        int dt = b2 & 3, st = (b2 >> 2) & 31, hh = (b2 >> 7) & 3, b = b2 >> 9;
        int t = threadIdx.x;
#pragma unroll
        for (int rep = 0; rep < 4; rep++) {        // float4 loads: 4 reps (was 16 scalar)
            int u = t + rep * 256;
            int ts = u >> 4, td = (u & 15) * 4;
            float4 x = *(const float4*)(v + ((long)b * S_ + st * 64 + ts) * E_
                                          + hh * DH_ + dt * 64 + td);
            tile[ts][td]     = f2bf(x.x);
            tile[ts][td + 1] = f2bf(x.y);
            tile[ts][td + 2] = f2bf(x.z);
            tile[ts][td + 3] = f2bf(x.w);
        }
        __syncthreads();
        long obase = ((long)(b * NH_ + hh) * DH_ + dt * 64) * S_ + st * 64;
#pragma unroll
        for (int rep = 0; rep < 8; rep++) {
            int idx = t + rep * 256;
            int dd = idx >> 5, sp = (idx & 31) * 2;
            short2 val;
            val.x = tile[sp][dd];
            val.y = tile[sp + 1][dd];
            *(short2*)(vt + obase + (long)dd * S_ + sp) = val;
        }
    }
}

// ---------------- scan: 1024 threads/seq -> 2 serial chunks
__global__ __launch_bounds__(1024)
void scan_kernel(const float* __restrict__ ig_ws, const float* __restrict__ fg_ws,
                 float* __restrict__ c_ws, float* __restrict__ a_ws,
                 float* __restrict__ M_ws) {
    __shared__ float wsum[16], wmax[16];
    int seq = blockIdx.x;
    int tid = threadIdx.x, w = tid >> 6, lane = tid & 63;
    long base = (long)seq * S_;
    float carryC = 0.f, carryM = -INFINITY;
    for (int ch = 0; ch < S_ / 1024; ch++) {
        int s = ch * 1024 + tid;
        float fgv = fg_ws[base + s];
        float lf = (fgv > 0.f) ? -log1pf(expf(-fgv)) : (fgv - log1pf(expf(fgv)));
        float x = lf;
        for (int d = 1; d < 64; d <<= 1) { float t = __shfl_up(x, d); if (lane >= d) x += t; }
        if (lane == 63) wsum[w] = x;
        __syncthreads();
        float pre = carryC;
        for (int j = 0; j < w; j++) pre += wsum[j];
        float c = pre + x;
        float a = ig_ws[base + s] - c;
        float m = a;
        for (int d = 1; d < 64; d <<= 1) { float t = __shfl_up(m, d); if (lane >= d) m = fmaxf(m, t); }
        if (lane == 63) wmax[w] = m;
        __syncthreads();
        float prem = carryM;
        for (int j = 0; j < w; j++) prem = fmaxf(prem, wmax[j]);
        float M = fmaxf(prem, m);
        c_ws[base + s] = c;
        a_ws[base + s] = a;
        M_ws[base + s] = M;
        float allsum = 0.f, allmax = -INFINITY;
        for (int j = 0; j < 16; j++) { allsum += wsum[j]; allmax = fmaxf(allmax, wmax[j]); }
        carryC += allsum;
        carryM = fmaxf(carryM, allmax);
        __syncthreads();
    }
}

// ================= split-K main (R11 loop verbatim) + in-block epilogue for nc==1.
// grid 384: seq = bid&7, local = bid>>3 in [0,48):
//   local <32: split qt = 31-(local>>1), chunk = local&1, pq=(qt-16)*2+chunk
//   local>=32: direct qt = 47-local, full range, epilogue in-block -> out
// LDS 72KB: K 32K | V 32K | P 8K (P reused as f32 scratch in epilogue)
__global__ __launch_bounds__(256)
void mlstm_sb1(const short* __restrict__ qbf, const short* __restrict__ kbf,
               const short* __restrict__ vt,
               const float* __restrict__ a_ws, const float* __restrict__ M_ws,
               const float* __restrict__ c_ws, const float* __restrict__ onw,
               float* __restrict__ num_ws, float* __restrict__ den_ws,
               float* __restrict__ out) {
    __shared__ __align__(16) char LDSb[73728];

    const int bid = blockIdx.x;
    const int seq = bid & 7;
    const int local = bid >> 3;
    int qt, kt0, kt1, pq;
    bool direct;
    if (local < 32) {
        qt = 31 - (local >> 1);
        int nkt = qt + 1;
        int c0 = (nkt + 1) >> 1;
        if ((local & 1) == 0) { kt0 = 0; kt1 = c0; } else { kt0 = c0; kt1 = nkt; }
        pq = (qt - 16) * 2 + (local & 1);
        direct = false;
    } else {
        qt = 47 - local;
        kt0 = 0; kt1 = qt + 1;
        pq = 0;
        direct = true;
    }

    const int tid = threadIdx.x;
    const int w  = tid >> 6;
    const int rg = w & 1;
    const int ct = w >> 1;
    const int l  = tid & 63;
    const int l31 = l & 31;
    const int h5  = l >> 5;
    const int h = seq & 3;
    const int b = seq >> 2;

    const long seqbase = (long)seq * S_ * DH_;
    const long gbase = (long)seq * S_;
    const int i0 = qt * 64;

    const char* kseq = (const char*)(kbf + seqbase);
    const char* vseq = (const char*)(vt + seqbase);

    int preK[8], preV[8];
#pragma unroll
    for (int i = 0; i < 8; i++) {
        int r = w * 16 + i * 2 + (l >> 5);
        preK[i] = r * 512 + (((l & 31) * 16) ^ ((r & 7) << 4));
        int d = w * 64 + i * 8 + (l >> 3);
        preV[i] = d * (S_ * 2) + (((l & 7) * 16) ^ ((d & 7) << 4));
    }

    float Mi[16], ci[16];
#pragma unroll
    for (int reg = 0; reg < 16; reg++) {
        int rowL = 32 * rg + (reg & 3) + 8 * (reg >> 2) + 4 * h5;
        Mi[reg] = M_ws[gbase + i0 + rowL];
        ci[reg] = c_ws[gbase + i0 + rowL];
    }

    // ---- stage Q through K region, pull A-frags
#pragma unroll
    for (int rep = 0; rep < 8; rep++) {
        int idx = tid + rep * 256;
        int r = idx >> 5, c = idx & 31;
        s16x8 val = *(const s16x8*)(qbf + seqbase + (long)(i0 + r) * DH_ + c * 8);
        int byte = (r * 512 + c * 16) ^ ((r & 7) << 4);
        *(s16x8*)(LDSb + byte) = val;
    }
    __syncthreads();
    bf16x8 qfrag[16];
    {
        int qrow = 32 * rg + l31;
        int qswz = (qrow & 7) << 4;
#pragma unroll
        for (int dc = 0; dc < 16; dc++)
            qfrag[dc] = *(const bf16x8*)(LDSb + ((qrow * 512 + dc * 32 + h5 * 16) ^ qswz));
    }
    __syncthreads();

    f32x16 oacc[4] = {};
    float denacc[16] = {};

    const char* Klds  = LDSb;
    const char* Vtlds = LDSb + 32768;
    char* Plds = LDSb + 65536;

    for (int kt = kt0; kt < kt1; kt++) {
        const int j0 = kt * 64;
        {
            const char* ks = kseq + (long)j0 * 512;
            const char* vs = vseq + (long)j0 * 2;
            char* kd = LDSb + w * 8192;
            char* vd = LDSb + 32768 + w * 8192;
#pragma unroll
            for (int i = 0; i < 8; i++) gload16(ks + preK[i], kd + i * 1024);
#pragma unroll
            for (int i = 0; i < 8; i++) gload16(vs + preV[i], vd + i * 1024);
        }
        float aj = a_ws[gbase + j0 + 32 * ct + l31];
        __syncthreads();

        // ---- QK^T
        f32x16 sacc = {};
        {
            int j = 32 * ct + l31;
            int jswz = (j & 7) << 4;
            int jbase = j * 512;
#pragma unroll
            for (int dc = 0; dc < 16; dc++) {
                bf16x8 kf = *(const bf16x8*)(Klds + ((jbase + dc * 32 + h5 * 16) ^ jswz));
                sacc = __builtin_amdgcn_mfma_f32_32x32x16_bf16(qfrag[dc], kf, sacc, 0, 0, 0);
            }
        }
        // ---- P
        {
            int jg = j0 + 32 * ct + l31;
#pragma unroll
            for (int reg = 0; reg < 16; reg++) {
                int rowL = 32 * rg + (reg & 3) + 8 * (reg >> 2) + 4 * h5;
                float p = sacc[reg] * 0.0625f * __expf(aj - Mi[reg]);
                if (jg > i0 + rowL) p = 0.f;
                denacc[reg] += p;
                int byte = (rowL * 128 + (32 * ct + l31) * 2) ^ ((rowL & 7) << 4);
                *(short*)(Plds + byte) = f2bf(p);
            }
        }
        __syncthreads();

        // ---- PV
        bf16x8 pfrag[4];
        {
            int prow = 32 * rg + l31;
            int pswz = (prow & 7) << 4;
#pragma unroll
            for (int k4 = 0; k4 < 4; k4++)
                pfrag[k4] = *(const bf16x8*)(Plds + ((prow * 128 + k4 * 32 + h5 * 16) ^ pswz));
        }
#pragma unroll
        for (int dt = 0; dt < 4; dt++) {
            int d = 128 * ct + 32 * dt + l31;
            int dbase = d * 128, dswz = (d & 7) << 4;
#pragma unroll
            for (int k4 = 0; k4 < 4; k4++) {
                bf16x8 vf = *(const bf16x8*)(Vtlds + ((dbase + k4 * 32 + h5 * 16) ^ dswz));
                oacc[dt] = __builtin_amdgcn_mfma_f32_32x32x16_bf16(pfrag[k4], vf, oacc[dt], 0, 0, 0);
            }
        }
        __syncthreads();
    }

    // ---- wave-local den reduction (over l31; both halves of each 32-group hold it)
    float dred[16];
#pragma unroll
    for (int reg = 0; reg < 16; reg++) {
        float dsum = denacc[reg];
        dsum += __shfl_xor(dsum, 1);
        dsum += __shfl_xor(dsum, 2);
        dsum += __shfl_xor(dsum, 4);
        dsum += __shfl_xor(dsum, 8);
        dsum += __shfl_xor(dsum, 16);
        dred[reg] = dsum;
    }

    if (!direct) {
        // ---- write partials (num layout identical to R11)
        const long cid = (long)pq * 8 + seq;
        const long nbase = cid * 64 * 256;
#pragma unroll
        for (int reg = 0; reg < 16; reg++) {
            int rowL = 32 * rg + (reg & 3) + 8 * (reg >> 2) + 4 * h5;
            if (l31 == 0) den_ws[cid * 128 + ct * 64 + rowL] = dred[reg];
        }
#pragma unroll
        for (int dt = 0; dt < 4; dt++) {
#pragma unroll
            for (int reg = 0; reg < 16; reg++) {
                int rowL = 32 * rg + (reg & 3) + 8 * (reg >> 2) + 4 * h5;
                num_ws[nbase + (long)rowL * 256 + 128 * ct + 32 * dt + l31] = oacc[dt][reg];
            }
        }
        return;
    }

    // ---- direct epilogue: cross-ct den exchange, normalize, two-pass LN, store
    float* fl = (float*)Plds;               // [0,128): den, [128,256): sum, [256,384): sumsq
#pragma unroll
    for (int reg = 0; reg < 16; reg++) {
        int rowL = 32 * rg + (reg & 3) + 8 * (reg >> 2) + 4 * h5;
        if (l31 == 0) fl[rowL * 2 + ct] = dred[reg];
    }
    __syncthreads();
    float inv[16];
#pragma unroll
    for (int reg = 0; reg < 16; reg++) {
        int rowL = 32 * rg + (reg & 3) + 8 * (reg >> 2) + 4 * h5;
        float den = fl[rowL * 2] + fl[rowL * 2 + 1];
        float lb = __expf(-ci[reg] - Mi[reg]);
        inv[reg] = 1.f / (fmaxf(fabsf(den), lb) + EPSF);
    }
    // x = oacc*inv; row sums
#pragma unroll
    for (int reg = 0; reg < 16; reg++) {
        float s = 0.f;
#pragma unroll
        for (int dt = 0; dt < 4; dt++) { oacc[dt][reg] *= inv[reg]; s += oacc[dt][reg]; }
        s += __shfl_xor(s, 1); s += __shfl_xor(s, 2); s += __shfl_xor(s, 4);
        s += __shfl_xor(s, 8); s += __shfl_xor(s, 16);
        int rowL = 32 * rg + (reg & 3) + 8 * (reg >> 2) + 4 * h5;
        if (l31 == 0) fl[128 + rowL * 2 + ct] = s;
    }
    __syncthreads();
    float mean[16];
#pragma unroll
    for (int reg = 0; reg < 16; reg++) {
        int rowL = 32 * rg + (reg & 3) + 8 * (reg >> 2) + 4 * h5;
        mean[reg] = (fl[128 + rowL * 2] + fl[128 + rowL * 2 + 1]) * (1.f / 256.f);
    }
#pragma unroll
    for (int reg = 0; reg < 16; reg++) {
        float vs = 0.f;
#pragma unroll
        for (int dt = 0; dt < 4; dt++) { float dx = oacc[dt][reg] - mean[reg]; vs += dx * dx; }
        vs += __shfl_xor(vs, 1); vs += __shfl_xor(vs, 2); vs += __shfl_xor(vs, 4);
        vs += __shfl_xor(vs, 8); vs += __shfl_xor(vs, 16);
        int rowL = 32 * rg + (reg & 3) + 8 * (reg >> 2) + 4 * h5;
        if (l31 == 0) fl[256 + rowL * 2 + ct] = vs;
    }
    __syncthreads();
#pragma unroll
    for (int dt = 0; dt < 4; dt++) {
        int dcol = 128 * ct + 32 * dt + l31;
        float wv = onw[h * DH_ + dcol];
#pragma unroll
        for (int reg = 0; reg < 16; reg++) {
            int rowL = 32 * rg + (reg & 3) + 8 * (reg >> 2) + 4 * h5;
            float var = (fl[256 + rowL * 2] + fl[256 + rowL * 2 + 1]) * (1.f / 256.f);
            float rstd = rsqrtf(var + EPSF);
            out[((long)b * S_ + i0 + rowL) * E_ + h * DH_ + dcol] =
                (oacc[dt][reg] - mean[reg]) * rstd * wv;
        }
    }
}

// ================= reduce (split tiles qt>=16 only): 2 chunks + normalizer + LN
// grid 256: seq = bid&7, qh = bid>>3 in [0,32): qt = 16+(qh>>1), half = qh&1
__global__ __launch_bounds__(256)
void reduce_kernel(const float* __restrict__ num_ws, const float* __restrict__ den_ws,
                   const float* __restrict__ c_ws, const float* __restrict__ M_ws,
                   const float* __restrict__ onw, float* __restrict__ out) {
    const int bid = blockIdx.x;
    const int seq = bid & 7;
    const int qh = bid >> 3;
    const int qt = 16 + (qh >> 1);
    const int half = qh & 1;
    const int h = seq & 3;
    const int b = seq >> 2;
    const int w = threadIdx.x >> 6;
    const int l = threadIdx.x & 63;
    const long gbase = (long)seq * S_;
    const long cid0 = (long)((qt - 16) * 2) * 8 + seq;
    const long cid1 = cid0 + 8;

    float4 w4 = *(const float4*)(onw + h * DH_ + l * 4);

    for (int rr = 0; rr < 8; rr++) {
        int row = half * 32 + w * 8 + rr;
        int s = qt * 64 + row;
        const float4 p0 = *(const float4*)(num_ws + cid0 * 16384 + (long)row * 256 + l * 4);
        const float4 p1 = *(const float4*)(num_ws + cid1 * 16384 + (long)row * 256 + l * 4);
        float4 acc = {p0.x + p1.x, p0.y + p1.y, p0.z + p1.z, p0.w + p1.w};
        float dsum = den_ws[cid0 * 128 + row] + den_ws[cid0 * 128 + 64 + row]
                   + den_ws[cid1 * 128 + row] + den_ws[cid1 * 128 + 64 + row];
        float lb = __expf(-c_ws[gbase + s] - M_ws[gbase + s]);
        float inv = 1.f / (fmaxf(fabsf(dsum), lb) + EPSF);
        float4 x = {acc.x * inv, acc.y * inv, acc.z * inv, acc.w * inv};
        float sum = x.x + x.y + x.z + x.w;
        sum += __shfl_xor(sum, 1); sum += __shfl_xor(sum, 2); sum += __shfl_xor(sum, 4);
        sum += __shfl_xor(sum, 8); sum += __shfl_xor(sum, 16); sum += __shfl_xor(sum, 32);
        float mean = sum * (1.f / 256.f);
        float vx = x.x - mean, vy = x.y - mean, vz = x.z - mean, vw = x.w - mean;
        float vs = vx * vx + vy * vy + vz * vz + vw * vw;
        vs += __shfl_xor(vs, 1); vs += __shfl_xor(vs, 2); vs += __shfl_xor(vs, 4);
        vs += __shfl_xor(vs, 8); vs += __shfl_xor(vs, 16); vs += __shfl_xor(vs, 32);
        float rstd = rsqrtf(vs * (1.f / 256.f) + EPSF);
        float4 o;
        o.x = vx * rstd * w4.x; o.y = vy * rstd * w4.y;
        o.z = vz * rstd * w4.z; o.w = vw * rstd * w4.w;
        *(float4*)(out + ((long)b * S_ + s) * E_ + h * DH_ + l * 4) = o;
    }
}

// ================= fallback mono kernel (proven R1 version) if ws too small
__global__ __launch_bounds__(256)
void mlstm_mono(const short* __restrict__ qbf, const short* __restrict__ kbf,
                const short* __restrict__ vt,
                const float* __restrict__ a_ws, const float* __restrict__ M_ws,
                const float* __restrict__ c_ws, const float* __restrict__ onw,
                float* __restrict__ out) {
    __shared__ __align__(16) short Klds[64 * 256];
    __shared__ __align__(16) short Vtlds[256 * 64];
    short* Plds = Klds;

    const int bid = blockIdx.x;
    const int seq = bid & 7;
    const int qt = bid >> 3;
    const int h = seq & 3;
    const int b = seq >> 2;
    const int tid = threadIdx.x;
    const int w = tid >> 6;
    const int l = tid & 63;
    const int l15 = l & 15;
    const int g = l >> 4;

    const long seqbase = (long)seq * S_ * DH_;
    const long gbase = (long)seq * S_;
    const int i0 = qt * 64;

    float Mi_r[4], ci_r[4];
#pragma unroll
    for (int r = 0; r < 4; r++) {
        int il = 16 * w + 4 * g + r;
        Mi_r[r] = M_ws[gbase + i0 + il];
        ci_r[r] = c_ws[gbase + i0 + il];
    }
#pragma unroll
    for (int rep = 0; rep < 8; rep++) {
        int idx = tid + rep * 256;
        int r = idx >> 5, c = idx & 31;
        s16x8 val = *(const s16x8*)(qbf + seqbase + (long)(i0 + r) * DH_ + c * 8);
        int byte = (r * 512 + c * 16) ^ ((r & 7) << 4);
        *(s16x8*)((char*)Klds + byte) = val;
    }
    __syncthreads();
    bf16x8 qfrag[8];
#pragma unroll
    for (int dc = 0; dc < 8; dc++) {
        int r = 16 * w + l15;
        int byte = (r * 512 + (8 * g + 32 * dc) * 2) ^ ((r & 7) << 4);
        qfrag[dc] = *(const bf16x8*)((const char*)Klds + byte);
    }
    __syncthreads();

    const f32x4 fzero = {0.f, 0.f, 0.f, 0.f};
    f32x4 oacc[16];
#pragma unroll
    for (int dt = 0; dt < 16; dt++) oacc[dt] = fzero;
    float den[4] = {0.f, 0.f, 0.f, 0.f};

    const int nkt = qt + 1;
    for (int kt = 0; kt < nkt; kt++) {
        const int j0 = kt * 64;
#pragma unroll
        for (int rep = 0; rep < 8; rep++) {
            int idx = tid + rep * 256;
            int r = idx >> 5, c = idx & 31;
            s16x8 val = *(const s16x8*)(kbf + seqbase + (long)(j0 + r) * DH_ + c * 8);
            int byte = (r * 512 + c * 16) ^ ((r & 7) << 4);
            *(s16x8*)((char*)Klds + byte) = val;
        }
#pragma unroll
        for (int rep = 0; rep < 8; rep++) {
            int idx = tid + rep * 256;
            int d = idx >> 3, c = idx & 7;
            s16x8 val = *(const s16x8*)(vt + seqbase + (long)d * S_ + j0 + c * 8);
            int byte = (d * 128 + c * 16) ^ ((d & 7) << 4);
            *(s16x8*)((char*)Vtlds + byte) = val;
        }
        float aj_ct[4];
#pragma unroll
        for (int ct = 0; ct < 4; ct++) aj_ct[ct] = a_ws[gbase + j0 + 16 * ct + l15];
        __syncthreads();

        f32x4 sacc[4];
#pragma unroll
        for (int ct = 0; ct < 4; ct++) sacc[ct] = fzero;
#pragma unroll
        for (int dc = 0; dc < 8; dc++) {
#pragma unroll
            for (int ct = 0; ct < 4; ct++) {
                int j = 16 * ct + l15;
                int byte = (j * 512 + (8 * g + 32 * dc) * 2) ^ ((j & 7) << 4);
                bf16x8 kf = *(const bf16x8*)((const char*)Klds + byte);
                sacc[ct] = __builtin_amdgcn_mfma_f32_16x16x32_bf16(qfrag[dc], kf, sacc[ct], 0, 0, 0);
            }
        }
        __syncthreads();

        const bool diag = (kt == qt);
#pragma unroll
        for (int ct = 0; ct < 4; ct++) {
            int jl = 16 * ct + l15;
            float aj = aj_ct[ct];
#pragma unroll
            for (int r = 0; r < 4; r++) {
                int il = 16 * w + 4 * g + r;
                float p = sacc[ct][r] * 0.0625f * __expf(aj - Mi_r[r]);
                if (diag && jl > il) p = 0.f;
                den[r] += p;
                int byte = (il * 128 + jl * 2) ^ ((il & 7) << 4);
                *(short*)((char*)Plds + byte) = f2bf(p);
            }
        }
        __syncthreads();

        bf16x8 pfrag[2];
#pragma unroll
        for (int jc = 0; jc < 2; jc++) {
            int i = 16 * w + l15;
            int byte = (i * 128 + (8 * g + 32 * jc) * 2) ^ ((i & 7) << 4);
            pfrag[jc] = *(const bf16x8*)((const char*)Plds + byte);
        }
#pragma unroll
        for (int dt = 0; dt < 16; dt++) {
#pragma unroll
            for (int jc = 0; jc < 2; jc++) {
                int d = 16 * dt + l15;
                int byte = (d * 128 + (8 * g + 32 * jc) * 2) ^ ((d & 7) << 4);
                bf16x8 vf = *(const bf16x8*)((const char*)Vtlds + byte);
                oacc[dt] = __builtin_amdgcn_mfma_f32_16x16x32_bf16(pfrag[jc], vf, oacc[dt], 0, 0, 0);
            }
        }
        __syncthreads();
    }

#pragma unroll
    for (int r = 0; r < 4; r++) {
        float dsum = den[r];
        dsum += __shfl_xor(dsum, 1);
        dsum += __shfl_xor(dsum, 2);
        dsum += __shfl_xor(dsum, 4);
        dsum += __shfl_xor(dsum, 8);
        int il = 16 * w + 4 * g + r;
        float lb = __expf(-ci_r[r] - Mi_r[r]);
        float inv = 1.f / (fmaxf(fabsf(dsum), lb) + EPSF);
        float x[16];
        float sum = 0.f;
#pragma unroll
        for (int dt = 0; dt < 16; dt++) { x[dt] = oacc[dt][r] * inv; sum += x[dt]; }
        sum += __shfl_xor(sum, 1); sum += __shfl_xor(sum, 2);
        sum += __shfl_xor(sum, 4); sum += __shfl_xor(sum, 8);
        float mean = sum * (1.f / 256.f);
        float vs = 0.f;
#pragma unroll
        for (int dt = 0; dt < 16; dt++) { float dx = x[dt] - mean; vs += dx * dx; }
        vs += __shfl_xor(vs, 1); vs += __shfl_xor(vs, 2);
        vs += __shfl_xor(vs, 4); vs += __shfl_xor(vs, 8);
        float rstd = rsqrtf(vs * (1.f / 256.f) + EPSF);
        long orow = ((long)b * S_ + i0 + il) * E_ + h * DH_;
#pragma unroll
        for (int dt = 0; dt < 16; dt++) {
            int d = 16 * dt + l15;
            out[orow + d] = (x[dt] - mean) * rstd * onw[h * DH_ + d];
        }
    }
}

extern "C" void kernel_launch(void* const* d_in, const int* in_sizes, int n_in,
                              void* d_out, int out_size, void* d_ws, size_t ws_size,
                              hipStream_t stream) {
    const float* q   = (const float*)d_in[0];
    const float* k   = (const float*)d_in[1];
    const float* v   = (const float*)d_in[2];
    const float* igk = (const float*)d_in[3];
    const float* igb = (const float*)d_in[4];
    const float* fgk = (const float*)d_in[5];
    const float* fgb = (const float*)d_in[6];
    const float* onw = (const float*)d_in[7];
    float* out = (float*)d_out;

    char* ws = (char*)d_ws;
    float* ig_ws = (float*)(ws);
    float* fg_ws = (float*)(ws + (64  << 10));
    float* c_ws  = (float*)(ws + (128 << 10));
    float* a_ws  = (float*)(ws + (192 << 10));
    float* M_ws  = (float*)(ws + (256 << 10));
    short* qbf   = (short*)(ws + (1L  << 20));
    short* kbf   = (short*)(ws + (9L  << 20));
    short* vtb   = (short*)(ws + (17L << 20));
    float* num_ws = (float*)(ws + (25L << 20));        // 256*64*256*4 = 16 MB
    float* den_ws = (float*)(ws + (60L << 20));        // 256*128*4 = 128 KB

    prep_kernel<<<1536, 256, 0, stream>>>(q, k, v, igk, igb, fgk, fgb,
                                          qbf, kbf, vtb, ig_ws, fg_ws);
    scan_kernel<<<8, 1024, 0, stream>>>(ig_ws, fg_ws, c_ws, a_ws, M_ws);

    if (ws_size >= (61L << 20)) {
        mlstm_sb1   <<<384, 256, 0, stream>>>(qbf, kbf, vtb, a_ws, M_ws, c_ws, onw,
                                              num_ws, den_ws, out);
        reduce_kernel<<<256, 256, 0, stream>>>(num_ws, den_ws, c_ws, M_ws, onw, out);
    } else {
        mlstm_mono  <<<256, 256, 0, stream>>>(qbf, kbf, vtb, a_ws, M_ws, c_ws, onw, out);
    }
}